// Round 14
// baseline (115.499 us; speedup 1.0000x reference)
//
#include <hip/hip_runtime.h>
#include <cstdint>

#define BB     4096
#define TT     96
#define NC     85
#define BLANKC 84
#define DD     64
#define ALPHA  0.05f
#define BT     (BB * TT)      // 393216
#define NF4    (TT * NC / 4)  // 2040 float4 per batch row
#define RPBA   4              // batch rows per k_amask block
#define NBA    (BB / RPBA)    // 1024 amask blocks
#define NBM    768            // k_main blocks (3/CU)
#define SL2    (NC * 34)      // float2 slice: 85 rows x 34 floats (8B-aligned)

// ---------------------------------------------------------------------------
// Kernel 1: fused argmax + CTC mask + histogram + DUP-FLAG precompute.
// 4 rows/block; wave w owns positions 12w..12w+11 of each row, 2-deep
// register pipeline (commit cur 4xf4 -> wave LDS, issue next row, scan cur).
// Scan: lanes 0..47, lane = 4r+q, FIXED-width-22 overlapping quarters
// (c0 = 21q) -> fully unrolled independent LDS reads; 2-step shuffle combine
// with lowest-col tie-break. Mask phase packs labm word = label | m<<31 and
// ORs bit30 (4-position-group dup flag, computed from lab_s) into word 0 of
// each group — removing all dup logic from k_main's hot loop.
// ---------------------------------------------------------------------------
__global__ __launch_bounds__(512) void k_amask(const float4* __restrict__ p4,
                                               const int* __restrict__ labels,
                                               unsigned* __restrict__ labm,
                                               int* __restrict__ hpartT,
                                               float* __restrict__ out) {
    __shared__ float rows[8][12 * NC];             // 32640 B
    __shared__ int   pls[RPBA * TT + 1];
    __shared__ int   lab_s[RPBA * TT];
    __shared__ int   h[NC];
    int tid  = threadIdx.x;
    int blk  = blockIdx.x;
    int lane = tid & 63;
    int w    = tid >> 6;
    if (tid < NC) h[tid] = 0;
    if (blk == 0 && tid == 480) out[0] = 0.f;
    int labreg = 0;
    if (tid < RPBA * TT) {
        labreg = labels[blk * RPBA * TT + tid];
        lab_s[tid] = labreg;                       // visible after B1
    }

    // prologue: issue row 0 chunk (255 f4 = positions 12w..12w+11)
    const float4* src = p4 + (size_t)(blk * RPBA) * NF4 + 255 * w;
    float4 v0 = src[lane];
    float4 v1 = src[lane + 64];
    float4 v2 = src[lane + 128];
    float4 v3 = src[min(lane + 192, 254)];

    for (int i = 0; i < RPBA; ++i) {
        float4* dst = (float4*)rows[w];
        dst[lane]       = v0;
        dst[lane + 64]  = v1;
        dst[lane + 128] = v2;
        if (lane < 63) dst[lane + 192] = v3;
        if (i + 1 < RPBA) {
            const float4* s2 = p4 + (size_t)(blk * RPBA + i + 1) * NF4 + 255 * w;
            v0 = s2[lane];
            v1 = s2[lane + 64];
            v2 = s2[lane + 128];
            v3 = s2[min(lane + 192, 254)];
        }
        // wave-private scan: lane = 4r+q; quarter q = [21q, 21q+22) (overlap ok)
        int r = lane >> 2, q = lane & 3;
        int c0 = q * 21;
        const float* row = rows[w] + (lane < 48 ? r : 0) * NC;
        float bv = row[c0]; int bc = c0;
#pragma unroll
        for (int k = 1; k < 22; ++k) {
            float v = row[c0 + k];
            if (v > bv) { bv = v; bc = c0 + k; }
        }
#pragma unroll
        for (int m = 1; m <= 2; m <<= 1) {
            float ov = __shfl_xor(bv, m);
            int   oc = __shfl_xor(bc, m);
            if (ov > bv || (ov == bv && oc < bc)) { bv = ov; bc = oc; }
        }
        if (lane < 48 && (lane & 3) == 0) pls[i * TT + w * 12 + r] = bc;
    }
    __syncthreads();                               // B1: pls + lab_s complete
    // mask + dup + labm pack + histogram (384 threads)
    if (tid < RPBA * TT) {
        int p  = pls[tid];
        int lp = tid % TT;
        int m  = (p != BLANKC) && (lp == TT - 1 || p != pls[tid + 1]);
        unsigned word = (unsigned)labreg | ((unsigned)m << 31);
        int g = tid & ~3;
        int l0 = lab_s[g], l1 = lab_s[g + 1], l2 = lab_s[g + 2], l3 = lab_s[g + 3];
        bool dup = (l0 == l1) | (l0 == l2) | (l0 == l3) |
                   (l1 == l2) | (l1 == l3) | (l2 == l3);
        if ((tid & 3) == 0 && dup) word |= 0x40000000u;
        labm[blk * RPBA * TT + tid] = word;
        atomicAdd(&h[labreg], m);                  // LDS only
    }
    __syncthreads();                               // B2: h complete
    if (tid < NC) hpartT[tid * NBA + blk] = h[tid];
}

// ---------------------------------------------------------------------------
// Kernel 2: masked feature segment-sum, float2-per-lane (substep = 4 pos x
// 32 dims = 128 elems, half the substeps of R13). 4 waves/block: dimh = w&1
// (32 dims), wg = w>>1 (position half); PRIVATE slice [85][34] (even stride
// -> 8B-aligned b64 LDS RMW). Dup flag comes precomputed in labm bit30.
// Double-buffered named-register pipeline (8 loads in flight). 768 blocks,
// 46.2 KB LDS -> 3 blocks/CU.
// ---------------------------------------------------------------------------
__global__ __launch_bounds__(256, 3) void k_main(const float* __restrict__ feat,
                                                 const unsigned* __restrict__ labm,
                                                 float* __restrict__ updp,
                                                 float* __restrict__ lossp) {
    __shared__ float sl[4 * SL2];                  // 46240 B
    __shared__ float lred[4];
    int tid = threadIdx.x;
    for (int i = tid; i < 4 * SL2; i += 256) sl[i] = 0.f;
    __syncthreads();

    int lane = tid & 63;
    int w    = tid >> 6;
    int dimh = w & 1;
    int wg   = w >> 1;
    int sub  = lane >> 4;                          // 4 positions
    int l16  = lane & 15;                          // 16 dim-pairs
    float* slice = sl + w * SL2;

    const int ppc = BT / (NBM * 2);                // 256
    const int nss = ppc / 16;                      // 16
    int p0 = (blockIdx.x * 2 + wg) * ppc;
    const float2* fb2 = (const float2*)feat + dimh * 16 + l16;

    float lsum = 0.f;
    float2 fA0, fA1, fA2, fA3, fB0, fB1, fB2, fB3;
    uint4  lA0, lA1, lA2, lA3, lB0, lB1, lB2, lB3;

#define ISSUE(P, f0, f1, f2, f3, q0, q1, q2, q3) do {            \
    int _p = (P);                                                \
    q0 = *(const uint4*)(labm + _p);                             \
    q1 = *(const uint4*)(labm + _p + 4);                         \
    q2 = *(const uint4*)(labm + _p + 8);                         \
    q3 = *(const uint4*)(labm + _p + 12);                        \
    f0 = fb2[(size_t)(_p + sub) * 32];                           \
    f1 = fb2[(size_t)(_p + 4 + sub) * 32];                       \
    f2 = fb2[(size_t)(_p + 8 + sub) * 32];                       \
    f3 = fb2[(size_t)(_p + 12 + sub) * 32];                      \
} while (0)

#define SUBSTEP(lv, fc) do {                                     \
    unsigned lw = (sub & 2) ? ((sub & 1) ? lv.w : lv.z)          \
                            : ((sub & 1) ? lv.y : lv.x);         \
    float m  = (float)(lw >> 31);                                \
    int   la = (int)(lw & 0xffu);                                \
    float cx = m * fc.x, cy = m * fc.y;                          \
    lsum = fmaf(cx, fc.x, lsum);                                 \
    lsum = fmaf(cy, fc.y, lsum);                                 \
    int a = la * 34 + l16 * 2;                                   \
    if (!((lv.x >> 30) & 1u)) {                                  \
        slice[a] += cx; slice[a + 1] += cy;                      \
    } else {                                                     \
        atomicAdd(&slice[a], cx); atomicAdd(&slice[a + 1], cy);  \
    }                                                            \
} while (0)

    ISSUE(p0, fA0, fA1, fA2, fA3, lA0, lA1, lA2, lA3);
    for (int ss = 0; ss < nss; ss += 2) {
        if (ss + 1 < nss)
            ISSUE(p0 + (ss + 1) * 16, fB0, fB1, fB2, fB3, lB0, lB1, lB2, lB3);
        SUBSTEP(lA0, fA0); SUBSTEP(lA1, fA1);
        SUBSTEP(lA2, fA2); SUBSTEP(lA3, fA3);
        if (ss + 1 < nss) {
            if (ss + 2 < nss)
                ISSUE(p0 + (ss + 2) * 16, fA0, fA1, fA2, fA3, lA0, lA1, lA2, lA3);
            SUBSTEP(lB0, fB0); SUBSTEP(lB1, fB1);
            SUBSTEP(lB2, fB2); SUBSTEP(lB3, fB3);
        }
    }
#undef ISSUE
#undef SUBSTEP
    __syncthreads();

    // flush: updp[i] = slice(dimh=dh,wg=0) + slice(dimh=dh,wg=1)
    float* myp = updp + (size_t)blockIdx.x * (NC * DD);
    for (int i = tid; i < NC * DD; i += 256) {
        int r = i >> 6, d = i & 63;
        int dh = d >> 5, d32 = d & 31;
        myp[i] = sl[dh * SL2 + r * 34 + d32] +
                 sl[(2 + dh) * SL2 + r * 34 + d32];
    }
#pragma unroll
    for (int off = 32; off; off >>= 1) lsum += __shfl_xor(lsum, off);
    if (lane == 0) lred[w] = lsum;
    __syncthreads();
    if (tid == 0)
        lossp[blockIdx.x] = lred[0] + lred[1] + lred[2] + lred[3];
}

// ---------------------------------------------------------------------------
// Kernel 3: grid NC*4+1. Block (j,q): counts[j] from hpartT[j][0..NBA),
// F over NBM partials for 16 dims, write centers, atomic 0.5*loss -> out[0].
// ---------------------------------------------------------------------------
__global__ __launch_bounds__(256) void k_reduce(const float* __restrict__ updp,
                                                const float* __restrict__ lossp,
                                                const float* __restrict__ centers,
                                                const int* __restrict__ hpartT,
                                                float* __restrict__ out) {
    __shared__ float sred[256];
    __shared__ float sr[4];
    __shared__ int   scnt;
    int tid = threadIdx.x;
    int bid = blockIdx.x;
    if (bid < NC * 4) {
        int j = bid >> 2, q = bid & 3;
        int cs = 0;
        for (int t = tid; t < NBA; t += 256) cs += hpartT[j * NBA + t];
#pragma unroll
        for (int off = 32; off; off >>= 1) cs += __shfl_xor(cs, off);
        int lane = tid & 63, wv = tid >> 6;
        if (lane == 0) ((int*)sred)[wv] = cs;
        __syncthreads();
        if (tid == 0)
            scnt = ((int*)sred)[0] + ((int*)sred)[1] +
                   ((int*)sred)[2] + ((int*)sred)[3];
        __syncthreads();
        float cnt = (float)scnt;
        int i = tid & 15;
        int c16 = tid >> 4;
        const int per = NBM >> 4;                  // 48
        int col = j * DD + q * 16 + i;
        float s = 0.f;
        for (int b = c16 * per; b < (c16 + 1) * per; ++b)
            s += updp[(size_t)b * (NC * DD) + col];
        sred[tid] = s;
        __syncthreads();
        if (tid < 16) {
            float F = 0.f;
#pragma unroll
            for (int cc = 0; cc < 16; ++cc) F += sred[cc * 16 + i];
            float c   = centers[col];
            float scale = ALPHA / (1.f + cnt);
            out[1 + col] = c - scale * (cnt * c - F);
            float lp = cnt * c * c - 2.f * c * F;
#pragma unroll
            for (int off = 8; off; off >>= 1) lp += __shfl_xor(lp, off);
            if (i == 0) atomicAdd(&out[0], 0.5f * lp);
        }
    } else {
        float s = 0.f;
        for (int t = tid; t < NBM; t += 256) s += lossp[t];
#pragma unroll
        for (int off = 32; off; off >>= 1) s += __shfl_xor(s, off);
        int lane = tid & 63, wv = tid >> 6;
        if (lane == 0) sr[wv] = s;
        __syncthreads();
        if (tid == 0) atomicAdd(&out[0], 0.5f * (sr[0] + sr[1] + sr[2] + sr[3]));
    }
}

// ---------------------------------------------------------------------------
extern "C" void kernel_launch(void* const* d_in, const int* in_sizes, int n_in,
                              void* d_out, int out_size, void* d_ws, size_t ws_size,
                              hipStream_t stream) {
    const float* preds    = (const float*)d_in[0];
    const float* features = (const float*)d_in[1];
    const int*   labels   = (const int*)d_in[2];
    const float* centers  = (const float*)d_in[3];
    float* out = (float*)d_out;

    char* ws = (char*)d_ws;
    unsigned* labm = (unsigned*)ws;                             // BT words (1.57 MB)
    int* hpartT    = (int*)(ws + 4 * (size_t)BT);               // NC*NBA ints (348 KB)
    size_t off0 = 4 * (size_t)BT + (size_t)NC * NBA * 4 + 512;
    float* lossp = (float*)(ws + off0);                         // NBM floats
    float* updp  = (float*)(ws + off0 + (size_t)NBM * 4 + 512); // 16.7 MB

    k_amask<<<NBA, 512, 0, stream>>>((const float4*)preds, labels, labm,
                                     hpartT, out);
    k_main<<<NBM, 256, 0, stream>>>(features, labm, updp, lossp);
    k_reduce<<<NC * 4 + 1, 256, 0, stream>>>(updp, lossp, centers, hpartT, out);
}

// Round 15
// 73.950 us; speedup vs baseline: 1.5618x; 1.5618x over previous
//
#include <hip/hip_runtime.h>
#include <cstdint>

#define BB     4096
#define TT     96
#define NC     85
#define BLANKC 84
#define DD     64
#define ALPHA  0.05f
#define BT     (BB * TT)      // 393216
#define NF4    (TT * NC / 4)  // 2040 float4 per batch row
#define RPBA   4              // batch rows per k_amask block
#define NBA    (BB / RPBA)    // 1024 amask blocks
#define NBM    512            // k_main blocks
#define SLICE_F (NC * 17)     // 1445 floats per wave-private slice

// ---------------------------------------------------------------------------
// Kernel 1: fused argmax + CTC mask + histogram + dup-flag precompute
// (R14 verbatim — the scan is fully unrolled fixed-width-22 overlapping
// quarters; dup flag for each 4-position group goes into bit30 of word 0).
// ---------------------------------------------------------------------------
__global__ __launch_bounds__(512) void k_amask(const float4* __restrict__ p4,
                                               const int* __restrict__ labels,
                                               unsigned* __restrict__ labm,
                                               int* __restrict__ hpartT,
                                               float* __restrict__ out) {
    __shared__ float rows[8][12 * NC];             // 32640 B
    __shared__ int   pls[RPBA * TT + 1];
    __shared__ int   lab_s[RPBA * TT];
    __shared__ int   h[NC];
    int tid  = threadIdx.x;
    int blk  = blockIdx.x;
    int lane = tid & 63;
    int w    = tid >> 6;
    if (tid < NC) h[tid] = 0;
    if (blk == 0 && tid == 480) out[0] = 0.f;
    int labreg = 0;
    if (tid < RPBA * TT) {
        labreg = labels[blk * RPBA * TT + tid];
        lab_s[tid] = labreg;
    }

    const float4* src = p4 + (size_t)(blk * RPBA) * NF4 + 255 * w;
    float4 v0 = src[lane];
    float4 v1 = src[lane + 64];
    float4 v2 = src[lane + 128];
    float4 v3 = src[min(lane + 192, 254)];

    for (int i = 0; i < RPBA; ++i) {
        float4* dst = (float4*)rows[w];
        dst[lane]       = v0;
        dst[lane + 64]  = v1;
        dst[lane + 128] = v2;
        if (lane < 63) dst[lane + 192] = v3;
        if (i + 1 < RPBA) {
            const float4* s2 = p4 + (size_t)(blk * RPBA + i + 1) * NF4 + 255 * w;
            v0 = s2[lane];
            v1 = s2[lane + 64];
            v2 = s2[lane + 128];
            v3 = s2[min(lane + 192, 254)];
        }
        int r = lane >> 2, q = lane & 3;
        int c0 = q * 21;
        const float* row = rows[w] + (lane < 48 ? r : 0) * NC;
        float bv = row[c0]; int bc = c0;
#pragma unroll
        for (int k = 1; k < 22; ++k) {
            float v = row[c0 + k];
            if (v > bv) { bv = v; bc = c0 + k; }
        }
#pragma unroll
        for (int m = 1; m <= 2; m <<= 1) {
            float ov = __shfl_xor(bv, m);
            int   oc = __shfl_xor(bc, m);
            if (ov > bv || (ov == bv && oc < bc)) { bv = ov; bc = oc; }
        }
        if (lane < 48 && (lane & 3) == 0) pls[i * TT + w * 12 + r] = bc;
    }
    __syncthreads();                               // B1: pls + lab_s complete
    if (tid < RPBA * TT) {
        int p  = pls[tid];
        int lp = tid % TT;
        int m  = (p != BLANKC) && (lp == TT - 1 || p != pls[tid + 1]);
        unsigned word = (unsigned)labreg | ((unsigned)m << 31);
        int g = tid & ~3;
        int l0 = lab_s[g], l1 = lab_s[g + 1], l2 = lab_s[g + 2], l3 = lab_s[g + 3];
        bool dup = (l0 == l1) | (l0 == l2) | (l0 == l3) |
                   (l1 == l2) | (l1 == l3) | (l2 == l3);
        if ((tid & 3) == 0 && dup) word |= 0x40000000u;
        labm[blk * RPBA * TT + tid] = word;
        atomicAdd(&h[labreg], m);
    }
    __syncthreads();                               // B2: h complete
    if (tid < NC) hpartT[tid * NBA + blk] = h[tid];
}

// ---------------------------------------------------------------------------
// Kernel 2: masked feature segment-sum — R13-proven shape (512 thr, scalar
// float per lane, wave-private slice [85][17], 8-deep named-register
// pipeline), with dup logic REMOVED from the hot loop (labm bit30 carries
// the precomputed 4-position-group dup flag).
// ---------------------------------------------------------------------------
__global__ __launch_bounds__(512, 6) void k_main(const float* __restrict__ feat,
                                                 const unsigned* __restrict__ labm,
                                                 float* __restrict__ updp,
                                                 float* __restrict__ lossp) {
    __shared__ float sl[8 * SLICE_F];              // 46240 B
    __shared__ float lred[8];
    int tid = threadIdx.x;
    for (int i = tid; i < 8 * SLICE_F; i += 512) sl[i] = 0.f;
    __syncthreads();

    int lane = tid & 63;
    int w    = tid >> 6;
    int dq   = w & 3;
    int wg   = w >> 2;
    int sub  = lane >> 4;
    int l16  = lane & 15;
    float* slice = sl + w * SLICE_F;

    const int ppc = BT / (NBM * 2);                // 384
    const int nss = ppc / 16;                      // 24
    int p0 = (blockIdx.x * 2 + wg) * ppc;
    const float* fbase = feat + dq * 16 + l16;

    float lsum = 0.f;
    float fA0, fA1, fA2, fA3, fB0, fB1, fB2, fB3;
    uint4 lA0, lA1, lA2, lA3, lB0, lB1, lB2, lB3;

#define ISSUE(P, f0, f1, f2, f3, q0, q1, q2, q3) do {            \
    int _p = (P);                                                \
    q0 = *(const uint4*)(labm + _p);                             \
    q1 = *(const uint4*)(labm + _p + 4);                         \
    q2 = *(const uint4*)(labm + _p + 8);                         \
    q3 = *(const uint4*)(labm + _p + 12);                        \
    f0 = fbase[(size_t)(_p + sub) * DD];                         \
    f1 = fbase[(size_t)(_p + 4 + sub) * DD];                     \
    f2 = fbase[(size_t)(_p + 8 + sub) * DD];                     \
    f3 = fbase[(size_t)(_p + 12 + sub) * DD];                    \
} while (0)

#define SUBSTEP(lv, fc) do {                                     \
    unsigned lw = (sub & 2) ? ((sub & 1) ? lv.w : lv.z)          \
                            : ((sub & 1) ? lv.y : lv.x);         \
    float m  = (float)(lw >> 31);                                \
    int   la = (int)(lw & 0xffu);                                \
    float c  = m * (fc);                                         \
    lsum = fmaf(c, (fc), lsum);                                  \
    int a = la * 17 + l16;                                       \
    if (!((lv.x >> 30) & 1u)) slice[a] += c;                     \
    else                      atomicAdd(&slice[a], c);           \
} while (0)

    ISSUE(p0, fA0, fA1, fA2, fA3, lA0, lA1, lA2, lA3);
    for (int ss = 0; ss < nss; ss += 2) {
        if (ss + 1 < nss)
            ISSUE(p0 + (ss + 1) * 16, fB0, fB1, fB2, fB3, lB0, lB1, lB2, lB3);
        SUBSTEP(lA0, fA0); SUBSTEP(lA1, fA1);
        SUBSTEP(lA2, fA2); SUBSTEP(lA3, fA3);
        if (ss + 1 < nss) {
            if (ss + 2 < nss)
                ISSUE(p0 + (ss + 2) * 16, fA0, fA1, fA2, fA3, lA0, lA1, lA2, lA3);
            SUBSTEP(lB0, fB0); SUBSTEP(lB1, fB1);
            SUBSTEP(lB2, fB2); SUBSTEP(lB3, fB3);
        }
    }
#undef ISSUE
#undef SUBSTEP
    __syncthreads();

    float* myp = updp + (size_t)blockIdx.x * (NC * DD);
    for (int i = tid; i < NC * DD; i += 512) {
        int r = i >> 6, d = i & 63;
        int qq = d >> 4, d16 = d & 15;
        myp[i] = sl[qq * SLICE_F + r * 17 + d16] +
                 sl[(qq + 4) * SLICE_F + r * 17 + d16];
    }
#pragma unroll
    for (int off = 32; off; off >>= 1) lsum += __shfl_xor(lsum, off);
    if (lane == 0) lred[w] = lsum;
    __syncthreads();
    if (tid == 0) {
        float s = 0.f;
#pragma unroll
        for (int ww = 0; ww < 8; ++ww) s += lred[ww];
        lossp[blockIdx.x] = s;
    }
}

// ---------------------------------------------------------------------------
// Kernel 3: grid NC*4+1. Block (j,q): counts[j] from hpartT[j][0..NBA),
// F over NBM partials for 16 dims, write centers, atomic 0.5*loss -> out[0].
// ---------------------------------------------------------------------------
__global__ __launch_bounds__(256) void k_reduce(const float* __restrict__ updp,
                                                const float* __restrict__ lossp,
                                                const float* __restrict__ centers,
                                                const int* __restrict__ hpartT,
                                                float* __restrict__ out) {
    __shared__ float sred[256];
    __shared__ float sr[4];
    __shared__ int   scnt;
    int tid = threadIdx.x;
    int bid = blockIdx.x;
    if (bid < NC * 4) {
        int j = bid >> 2, q = bid & 3;
        int cs = 0;
        for (int t = tid; t < NBA; t += 256) cs += hpartT[j * NBA + t];
#pragma unroll
        for (int off = 32; off; off >>= 1) cs += __shfl_xor(cs, off);
        int lane = tid & 63, wv = tid >> 6;
        if (lane == 0) ((int*)sred)[wv] = cs;
        __syncthreads();
        if (tid == 0)
            scnt = ((int*)sred)[0] + ((int*)sred)[1] +
                   ((int*)sred)[2] + ((int*)sred)[3];
        __syncthreads();
        float cnt = (float)scnt;
        int i = tid & 15;
        int c16 = tid >> 4;
        const int per = NBM >> 4;                  // 32
        int col = j * DD + q * 16 + i;
        float s = 0.f;
        for (int b = c16 * per; b < (c16 + 1) * per; ++b)
            s += updp[(size_t)b * (NC * DD) + col];
        sred[tid] = s;
        __syncthreads();
        if (tid < 16) {
            float F = 0.f;
#pragma unroll
            for (int cc = 0; cc < 16; ++cc) F += sred[cc * 16 + i];
            float c   = centers[col];
            float scale = ALPHA / (1.f + cnt);
            out[1 + col] = c - scale * (cnt * c - F);
            float lp = cnt * c * c - 2.f * c * F;
#pragma unroll
            for (int off = 8; off; off >>= 1) lp += __shfl_xor(lp, off);
            if (i == 0) atomicAdd(&out[0], 0.5f * lp);
        }
    } else {
        float s = 0.f;
        for (int t = tid; t < NBM; t += 256) s += lossp[t];
#pragma unroll
        for (int off = 32; off; off >>= 1) s += __shfl_xor(s, off);
        int lane = tid & 63, wv = tid >> 6;
        if (lane == 0) sr[wv] = s;
        __syncthreads();
        if (tid == 0) atomicAdd(&out[0], 0.5f * (sr[0] + sr[1] + sr[2] + sr[3]));
    }
}

// ---------------------------------------------------------------------------
extern "C" void kernel_launch(void* const* d_in, const int* in_sizes, int n_in,
                              void* d_out, int out_size, void* d_ws, size_t ws_size,
                              hipStream_t stream) {
    const float* preds    = (const float*)d_in[0];
    const float* features = (const float*)d_in[1];
    const int*   labels   = (const int*)d_in[2];
    const float* centers  = (const float*)d_in[3];
    float* out = (float*)d_out;

    char* ws = (char*)d_ws;
    unsigned* labm = (unsigned*)ws;                             // BT words (1.57 MB)
    int* hpartT    = (int*)(ws + 4 * (size_t)BT);               // NC*NBA ints (348 KB)
    size_t off0 = 4 * (size_t)BT + (size_t)NC * NBA * 4 + 512;
    float* lossp = (float*)(ws + off0);                         // NBM floats
    float* updp  = (float*)(ws + off0 + (size_t)NBM * 4 + 512); // 11.1 MB

    k_amask<<<NBA, 512, 0, stream>>>((const float4*)preds, labels, labm,
                                     hpartT, out);
    k_main<<<NBM, 512, 0, stream>>>(features, labm, updp, lossp);
    k_reduce<<<NC * 4 + 1, 256, 0, stream>>>(updp, lossp, centers, hpartT, out);
}